// Round 1
// baseline (51569.122 us; speedup 1.0000x reference)
//
// Round 1: persistent cooperative 2-layer LSTM, f16 MFMA, 1 grid barrier/step.
// 64 L0 blocks (nh=24 h0-cols, K'=1600 incl. x+pad) + 192 L1 blocks (nh=16,
// M-split x2, K=3072 fused [h0|h1]). c-state fp32 in LDS; h published fp16.
// Weights repacked fp16 per-block by convert kernel into d_ws (~59 MB).
#include <hip/hip_runtime.h>

#define TSTEPS 1024
#define BATCH  128
#define HDIM   1536
#define G4     6144
#define K0P    1600   // L0 packed K: [0,6)=x, [6,64)=0, [64,1600)=W_hh0
#define K1P    3072   // L1 packed K: [0,1536)=W_ih1, [1536,3072)=W_hh1

typedef _Float16 f16x8 __attribute__((ext_vector_type(8)));
typedef float    f32x4 __attribute__((ext_vector_type(4)));

// ---- workspace layout (bytes) ----
#define OFF_H0   256ul
#define OFF_H1   (OFF_H0 + 2ul*BATCH*HDIM*2)          // 786688
#define OFF_WP0  (OFF_H1 + 2ul*BATCH*HDIM*2)          // 1573120
#define OFF_WP1  (OFF_WP0 + (size_t)G4*K0P*2)         // 21233920
#define OFF_WLP  (OFF_WP1 + (size_t)G4*K1P*2)         // 58982656
#define WS_NEED  (OFF_WLP + 16ul*HDIM*2)              // 59031808

#define MFMA(a,b,c) __builtin_amdgcn_mfma_f32_16x16x32_f16(a,b,c,0,0,0)

__device__ __forceinline__ float sgf(float x) { return 1.f/(1.f + __expf(-x)); }
__device__ __forceinline__ float thf(float x) { float e = __expf(2.f*x); return 1.f - 2.f/(e+1.f); }

__device__ __forceinline__ void gld16(const _Float16* g, char* lds) {
  __builtin_amdgcn_global_load_lds(
      (const __attribute__((address_space(1))) unsigned int*)g,
      (__attribute__((address_space(3))) unsigned int*)lds, 16, 0, 0);
}

__device__ __forceinline__ void grid_bar(unsigned* cnt, unsigned target) {
  __syncthreads();                      // drains vmcnt (h stores in L2)
  if (threadIdx.x == 0) {
    __hip_atomic_fetch_add(cnt, 1u, __ATOMIC_RELEASE, __HIP_MEMORY_SCOPE_AGENT); // wbL2
    while (__hip_atomic_load(cnt, __ATOMIC_RELAXED, __HIP_MEMORY_SCOPE_AGENT) < target)
      __builtin_amdgcn_s_sleep(2);
    __builtin_amdgcn_fence(__ATOMIC_ACQUIRE, "agent");  // invL1+invL2 once
  }
  __syncthreads();
}

// ---- weight repack fp32 -> fp16, per-block packed rows ----
__global__ void convert_weights(const float* __restrict__ Wih0, const float* __restrict__ Whh0,
                                const float* __restrict__ Wih1, const float* __restrict__ Whh1,
                                const float* __restrict__ Wlin,
                                _Float16* __restrict__ Wp0, _Float16* __restrict__ Wp1,
                                _Float16* __restrict__ Wlp) {
  const unsigned N0 = (unsigned)G4*K0P, N1 = (unsigned)G4*K1P, N2 = 16u*HDIM;
  const unsigned NT = N0 + N1 + N2;
  for (unsigned i = blockIdx.x*blockDim.x + threadIdx.x; i < NT; i += gridDim.x*blockDim.x) {
    if (i < N0) {
      unsigned R = i / K0P, kk = i - R*K0P;
      unsigned g = R / 96, p = R - g*96;
      unsigned qq = p / 24, j = 24*g + (p - 24*qq);
      unsigned srow = qq*HDIM + j;
      float v;
      if (kk < 6)        v = Wih0[srow*6 + kk];
      else if (kk < 64)  v = 0.f;
      else               v = Whh0[(size_t)srow*HDIM + (kk-64)];
      Wp0[i] = (_Float16)v;
    } else if (i < N0 + N1) {
      unsigned ii = i - N0;
      unsigned R = ii / K1P, kk = ii - R*K1P;
      unsigned G = R >> 6, p = R & 63;
      unsigned qq = p >> 4, j = 16*G + (p & 15);
      unsigned srow = qq*HDIM + j;
      float v = (kk < HDIM) ? Wih1[(size_t)srow*HDIM + kk]
                            : Whh1[(size_t)srow*HDIM + (kk-HDIM)];
      Wp1[ii] = (_Float16)v;
    } else {
      unsigned ii = i - N0 - N1;
      unsigned r = ii / HDIM, k = ii - r*HDIM;
      Wlp[ii] = (_Float16)(r < 5 ? Wlin[r*HDIM + k] : 0.f);
    }
  }
}

__global__ __launch_bounds__(256, 1) void lstm_persistent(
    const float* __restrict__ xall,
    const float* __restrict__ bih0, const float* __restrict__ bhh0,
    const float* __restrict__ bih1, const float* __restrict__ bhh1,
    const float* __restrict__ blin,
    const _Float16* __restrict__ Wp0, const _Float16* __restrict__ Wp1,
    const _Float16* __restrict__ Wlp,
    _Float16* __restrict__ h0b, _Float16* __restrict__ h1b,
    unsigned* __restrict__ cnt, float* __restrict__ out)
{
  __shared__ __align__(16) char smem[45568];
  char*  unionR = smem;                    // 32KB: A dbuf (2x16KB) | gates | final partials
  float* cst    = (float*)(smem + 32768);  // c-state: L0 128x24, L1 64x16 (fp32, persistent)
  float* bg     = (float*)(smem + 45056);  // packed bias

  const int tid = threadIdx.x;
  const int w = tid >> 6, lane = tid & 63, q = lane >> 4, l15 = lane & 15;
  const int bid = blockIdx.x;
  const int mw = w & 1, nw = w >> 1;
  const int BH = BATCH*HDIM;
  unsigned barc = 0;

  if (bid < 64) {
    // ================= LAYER 0 block: M=128, N=96 (4 gates x 24 cols), K'=1600
    const int g = bid, c0 = 24*g;
    for (int p = tid; p < 96; p += 256) {
      int qq = p/24, j = c0 + p - 24*qq;
      int srow = qq*HDIM + j;
      bg[p] = bih0[srow] + bhh0[srow];
    }
    for (int i = tid; i < BATCH*24; i += 256) cst[i] = 0.f;
    __syncthreads();

    int pcol[3]; const _Float16* Brow[3]; float bv[3];
#pragma unroll
    for (int nt = 0; nt < 3; ++nt) {
      pcol[nt] = (nw + 2*nt)*16 + l15;
      Brow[nt] = Wp0 + (size_t)(g*96 + pcol[nt])*K0P + q*8;
      bv[nt]   = bg[pcol[nt]];
    }
    int addrA[4][2];
#pragma unroll
    for (int mt = 0; mt < 4; ++mt) {
      int m = (mw*4 + mt)*16 + l15;
#pragma unroll
      for (int ks = 0; ks < 2; ++ks) {
        int u = ks*4 + q;
        addrA[mt][ks] = 128*m + 16*(u ^ (m & 7));   // XOR swizzle -> 2-way (free)
      }
    }
    int stg_row[4], stg_koff[4];
#pragma unroll
    for (int rep = 0; rep < 4; ++rep) {
      int slot = rep*256 + tid;
      int m = slot >> 3, cs2 = slot & 7;
      stg_row[rep]  = m;
      stg_koff[rep] = (cs2 ^ (m & 7))*8;
    }

    for (int s = 0; s < TSTEPS; ++s) {
      const _Float16* h0r = h0b + ((s+1)&1)*BH;   // h0(s-1)
      _Float16*       h0w = h0b + (s&1)*BH;       // h0(s)
      const float*    xs  = xall + (size_t)s*BATCH*6;

      // stage chunk0 (x | zeros) into buf0, swizzled
#pragma unroll
      for (int rep = 0; rep < 4; ++rep) {
        int slot = rep*256 + tid;
        int m = stg_row[rep], qs = stg_koff[rep] >> 3;
        f16x8 v = {0,0,0,0,0,0,0,0};
        if (qs == 0) {
#pragma unroll
          for (int j = 0; j < 6; ++j) v[j] = (_Float16)xs[m*6 + j];
        }
        *(f16x8*)(unionR + slot*16) = v;
      }
      f16x8 bcur[3][2], bnxt[3][2];
#pragma unroll
      for (int nt = 0; nt < 3; ++nt)
#pragma unroll
        for (int ks = 0; ks < 2; ++ks)
          bcur[nt][ks] = *(const f16x8*)(Brow[nt] + ks*32);
      f32x4 acc[4][3];
#pragma unroll
      for (int mt = 0; mt < 4; ++mt)
#pragma unroll
        for (int nt = 0; nt < 3; ++nt) {
          f32x4 z = {bv[nt], bv[nt], bv[nt], bv[nt]};
          acc[mt][nt] = z;
        }
      __syncthreads();

      int cur = 0;
      for (int c = 0; c < 25; ++c) {
        if (c < 24) {
          char* dbase = unionR + (cur^1)*16384;
#pragma unroll
          for (int rep = 0; rep < 4; ++rep)
            gld16(h0r + (size_t)stg_row[rep]*HDIM + c*64 + stg_koff[rep],
                  dbase + (rep*256 + w*64)*16);
#pragma unroll
          for (int nt = 0; nt < 3; ++nt)
#pragma unroll
            for (int ks = 0; ks < 2; ++ks)
              bnxt[nt][ks] = *(const f16x8*)(Brow[nt] + (size_t)(c+1)*64 + ks*32);
        }
        char* cbase = unionR + cur*16384;
#pragma unroll
        for (int ks = 0; ks < 2; ++ks) {
          f16x8 a[4];
#pragma unroll
          for (int mt = 0; mt < 4; ++mt) a[mt] = *(const f16x8*)(cbase + addrA[mt][ks]);
#pragma unroll
          for (int mt = 0; mt < 4; ++mt)
#pragma unroll
            for (int nt = 0; nt < 3; ++nt)
              acc[mt][nt] = MFMA(a[mt], bcur[nt][ks], acc[mt][nt]);
        }
        __syncthreads();
        cur ^= 1;
#pragma unroll
        for (int nt = 0; nt < 3; ++nt)
#pragma unroll
          for (int ks = 0; ks < 2; ++ks) bcur[nt][ks] = bnxt[nt][ks];
      }

      // epilogue: gates -> LDS (two 64-row halves) -> cell update -> h fp16
      float* gates = (float*)unionR;   // [64][97]
      for (int r = 0; r < 2; ++r) {
        if (mw == r) {
#pragma unroll
          for (int mt = 0; mt < 4; ++mt) {
            int mrow = mt*16 + q*4;
#pragma unroll
            for (int nt = 0; nt < 3; ++nt)
#pragma unroll
              for (int rg = 0; rg < 4; ++rg)
                gates[(mrow+rg)*97 + pcol[nt]] = acc[mt][nt][rg];
          }
        }
        __syncthreads();
        for (int e = tid; e < 64*24; e += 256) {
          int j = e % 24, b = e / 24;
          float ig = gates[b*97 + j];
          float fg = gates[b*97 + 24 + j];
          float gg = gates[b*97 + 48 + j];
          float og = gates[b*97 + 72 + j];
          int bgl = r*64 + b;
          float co = cst[bgl*24 + j];
          float cn = sgf(fg)*co + sgf(ig)*thf(gg);
          cst[bgl*24 + j] = cn;
          h0w[(size_t)bgl*HDIM + c0 + j] = (_Float16)(sgf(og)*thf(cn));
        }
        __syncthreads();
      }
      barc += 256; grid_bar(cnt, barc);
    }
    barc += 256; grid_bar(cnt, barc);   // slot TSTEPS (idle)
  } else {
    // ================= LAYER 1 block: M=64 (batch half), N=64, K=3072
    const int idx = bid - 64, g1 = idx >> 1, mh = idx & 1, c0 = 16*g1;
    for (int p = tid; p < 64; p += 256) {
      int srow = (p >> 4)*HDIM + c0 + (p & 15);
      bg[p] = bih1[srow] + bhh1[srow];
    }
    for (int i = tid; i < 64*16; i += 256) cst[i] = 0.f;
    __syncthreads();

    int pcol[2]; const _Float16* Brow[2]; float bv[2];
#pragma unroll
    for (int nt = 0; nt < 2; ++nt) {
      pcol[nt] = (2*nw + nt)*16 + l15;
      Brow[nt] = Wp1 + (size_t)(g1*64 + pcol[nt])*K1P + q*8;
      bv[nt]   = bg[pcol[nt]];
    }
    int addrA[2][4];
#pragma unroll
    for (int mt = 0; mt < 2; ++mt) {
      int m = (mw*2 + mt)*16 + l15;
#pragma unroll
      for (int ks = 0; ks < 4; ++ks) {
        int u = ks*4 + q;
        addrA[mt][ks] = 256*m + 16*(u ^ (m & 15));
      }
    }
    int stg_row[4], stg_koff[4];
#pragma unroll
    for (int rep = 0; rep < 4; ++rep) {
      int slot = rep*256 + tid;
      int m = slot >> 4, cs2 = slot & 15;
      stg_row[rep]  = m;
      stg_koff[rep] = (cs2 ^ (m & 15))*8;
    }

    barc += 256; grid_bar(cnt, barc);   // slot 0 (idle)
    for (int s = 1; s <= TSTEPS; ++s) {
      const _Float16* h0r = h0b + ((s-1)&1)*BH;   // h0(s-1)
      const _Float16* h1r = h1b + (s&1)*BH;       // h1(s-2)
      _Float16*       h1w = h1b + ((s-1)&1)*BH;   // h1(s-1)

      char* dbase0 = unionR;
#pragma unroll
      for (int rep = 0; rep < 4; ++rep)
        gld16(h0r + (size_t)(64*mh + stg_row[rep])*HDIM + stg_koff[rep],
              dbase0 + (rep*256 + w*64)*16);
      f16x8 bcur[2][4], bnxt[2][4];
#pragma unroll
      for (int nt = 0; nt < 2; ++nt)
#pragma unroll
        for (int ks = 0; ks < 4; ++ks)
          bcur[nt][ks] = *(const f16x8*)(Brow[nt] + ks*32);
      f32x4 acc[2][2];
#pragma unroll
      for (int mt = 0; mt < 2; ++mt)
#pragma unroll
        for (int nt = 0; nt < 2; ++nt) {
          f32x4 z = {bv[nt], bv[nt], bv[nt], bv[nt]};
          acc[mt][nt] = z;
        }
      __syncthreads();

      int cur = 0;
      for (int c = 0; c < 24; ++c) {
        if (c < 23) {
          int cc = c + 1;
          const _Float16* sbase = (cc < 12) ? (h0r + cc*128) : (h1r + (cc-12)*128);
          char* dbase = unionR + (cur^1)*16384;
#pragma unroll
          for (int rep = 0; rep < 4; ++rep)
            gld16(sbase + (size_t)(64*mh + stg_row[rep])*HDIM + stg_koff[rep],
                  dbase + (rep*256 + w*64)*16);
#pragma unroll
          for (int nt = 0; nt < 2; ++nt)
#pragma unroll
            for (int ks = 0; ks < 4; ++ks)
              bnxt[nt][ks] = *(const f16x8*)(Brow[nt] + (size_t)cc*128 + ks*32);
        }
        char* cbase = unionR + cur*16384;
#pragma unroll
        for (int ks = 0; ks < 4; ++ks) {
          f16x8 a[2];
#pragma unroll
          for (int mt = 0; mt < 2; ++mt) a[mt] = *(const f16x8*)(cbase + addrA[mt][ks]);
#pragma unroll
          for (int mt = 0; mt < 2; ++mt)
#pragma unroll
            for (int nt = 0; nt < 2; ++nt)
              acc[mt][nt] = MFMA(a[mt], bcur[nt][ks], acc[mt][nt]);
        }
        __syncthreads();
        cur ^= 1;
#pragma unroll
        for (int nt = 0; nt < 2; ++nt)
#pragma unroll
          for (int ks = 0; ks < 4; ++ks) bcur[nt][ks] = bnxt[nt][ks];
      }

      float* gates = (float*)unionR;   // [64][65]
#pragma unroll
      for (int mt = 0; mt < 2; ++mt) {
        int mrow = (mw*2 + mt)*16 + q*4;
#pragma unroll
        for (int nt = 0; nt < 2; ++nt)
#pragma unroll
          for (int rg = 0; rg < 4; ++rg)
            gates[(mrow+rg)*65 + pcol[nt]] = acc[mt][nt][rg];
      }
      __syncthreads();
      for (int e = tid; e < 64*16; e += 256) {
        int j = e & 15, b = e >> 4;
        float ig = gates[b*65 + j];
        float fg = gates[b*65 + 16 + j];
        float gg = gates[b*65 + 32 + j];
        float og = gates[b*65 + 48 + j];
        float co = cst[e];
        float cn = sgf(fg)*co + sgf(ig)*thf(gg);
        cst[e] = cn;
        h1w[(size_t)(64*mh + b)*HDIM + c0 + j] = (_Float16)(sgf(og)*thf(cn));
      }
      barc += 256; grid_bar(cnt, barc);
    }
  }

  // ---- final linear: out = h1(T-1) @ Wlin^T + blin, block 0 only ----
  if (bid == 0) {
    const _Float16* h1r = h1b + ((TSTEPS-1)&1)*BH;
    f32x4 acc[8];
#pragma unroll
    for (int i = 0; i < 8; ++i) { f32x4 z = {0,0,0,0}; acc[i] = z; }
    for (int c = w*12; c < w*12 + 12; ++c) {
      f16x8 bf = *(const f16x8*)(Wlp + (size_t)l15*HDIM + c*32 + q*8);
#pragma unroll
      for (int mt = 0; mt < 8; ++mt) {
        f16x8 a = *(const f16x8*)(h1r + (size_t)(mt*16 + l15)*HDIM + c*32 + q*8);
        acc[mt] = MFMA(a, bf, acc[mt]);
      }
    }
    float* pl = (float*)unionR;  // [4 waves][128][16]
#pragma unroll
    for (int mt = 0; mt < 8; ++mt)
#pragma unroll
      for (int rg = 0; rg < 4; ++rg)
        pl[w*2048 + (mt*16 + q*4 + rg)*16 + l15] = acc[mt][rg];
    __syncthreads();
    for (int e = tid; e < 640; e += 256) {
      int b = e/5, o = e - 5*b;
      out[e] = blin[o] + pl[b*16+o] + pl[2048 + b*16+o] + pl[4096 + b*16+o] + pl[6144 + b*16+o];
    }
  }
}

extern "C" void kernel_launch(void* const* d_in, const int* in_sizes, int n_in,
                              void* d_out, int out_size, void* d_ws, size_t ws_size,
                              hipStream_t stream) {
  (void)in_sizes; (void)n_in; (void)out_size;
  if (ws_size < WS_NEED) return;  // workspace too small -> visible failure

  const float* x    = (const float*)d_in[0];
  const float* Wih0 = (const float*)d_in[1];
  const float* Whh0 = (const float*)d_in[2];
  const float* bih0 = (const float*)d_in[3];
  const float* bhh0 = (const float*)d_in[4];
  const float* Wih1 = (const float*)d_in[5];
  const float* Whh1 = (const float*)d_in[6];
  const float* bih1 = (const float*)d_in[7];
  const float* bhh1 = (const float*)d_in[8];
  const float* Wlin = (const float*)d_in[9];
  const float* blin = (const float*)d_in[10];

  char* ws = (char*)d_ws;
  unsigned*  cnt = (unsigned*)ws;
  _Float16*  h0b = (_Float16*)(ws + OFF_H0);
  _Float16*  h1b = (_Float16*)(ws + OFF_H1);
  _Float16*  Wp0 = (_Float16*)(ws + OFF_WP0);
  _Float16*  Wp1 = (_Float16*)(ws + OFF_WP1);
  _Float16*  Wlp = (_Float16*)(ws + OFF_WLP);
  float*     out = (float*)d_out;

  // zero barrier counter + both h ping-pong buffers
  hipMemsetAsync(ws, 0, OFF_WP0, stream);
  hipLaunchKernelGGL(convert_weights, dim3(4096), dim3(256), 0, stream,
                     Wih0, Whh0, Wih1, Whh1, Wlin, Wp0, Wp1, Wlp);

  void* args[13];
  args[0]  = (void*)&x;    args[1]  = (void*)&bih0; args[2]  = (void*)&bhh0;
  args[3]  = (void*)&bih1; args[4]  = (void*)&bhh1; args[5]  = (void*)&blin;
  args[6]  = (void*)&Wp0;  args[7]  = (void*)&Wp1;  args[8]  = (void*)&Wlp;
  args[9]  = (void*)&h0b;  args[10] = (void*)&h1b;  args[11] = (void*)&cnt;
  args[12] = (void*)&out;
  hipLaunchCooperativeKernel((const void*)lstm_persistent, dim3(256), dim3(256),
                             args, 0u, stream);
}

// Round 3
// 29673.056 us; speedup vs baseline: 1.7379x; 1.7379x over previous
//
// Round 3: persistent cooperative 2-layer LSTM, weights RESIDENT IN VGPRS.
// 96 L0 blocks (N=64 gate-cols, K=1600 incl x-pad) + 128 L1 blocks (N=48,
// K=3072, 16 chunks parked in LDS). h staged via global_load_lds windows
// (BK=128, 3 bufs, dist-2 prefetch, manual vmcnt waits + lgkm-only barriers).
// K-split round-robin across the 4 waves; staggered LDS reduction; 1 grid
// barrier/step (proven round-1 mechanism, 224 blocks).
#include <hip/hip_runtime.h>

#define TSTEPS 1024
#define BATCH  128
#define HDIM   1536
#define NBLK   224
#define NB_L0  96
#define K0P    1600    // L0 packed K: [0,64)=x+pad, [64,1600)=W_hh0
#define K1P    3072    // L1 packed K: [0,1536)=W_ih1, [1536,3072)=W_hh1

typedef _Float16 f16x8 __attribute__((ext_vector_type(8)));
typedef float    f32x4 __attribute__((ext_vector_type(4)));

// ---- workspace layout (bytes) ----
#define OFF_H0   256ul
#define OFF_H1   (OFF_H0 + 2ul*BATCH*HDIM*2)            // 786688
#define OFF_WP0  (OFF_H1 + 2ul*BATCH*HDIM*2)            // 1573120
#define OFF_WP1  (OFF_WP0 + 96ul*64*K0P*2)              // 21233920
#define OFF_WLP  (OFF_WP1 + 128ul*48*K1P*2)             // 58982656
#define WS_NEED  (OFF_WLP + 16ul*HDIM*2)                // 59031808

// ---- dynamic LDS layout (bytes) ----
#define SM_PARK  98304     // 3 x 32KB staging windows first
#define SM_CST   147456    // park: 16 chunks x 3KB = 48KB (L1 only)
#define SM_BG    155648    // cst: up to 8KB
#define SM_BYTES 155904

#define MFMA(a,b,c) __builtin_amdgcn_mfma_f32_16x16x32_f16(a,b,c,0,0,0)
#define LDSBAR()  asm volatile("s_waitcnt lgkmcnt(0)\n\ts_barrier" ::: "memory")
#define WAITVM8() asm volatile("s_waitcnt vmcnt(8)" ::: "memory")
#define WAITVM0() asm volatile("s_waitcnt vmcnt(0)" ::: "memory")

__device__ __forceinline__ float sgf(float x) { return 1.f/(1.f + __expf(-x)); }
__device__ __forceinline__ float thf(float x) { float e = __expf(2.f*x); return 1.f - 2.f/(e+1.f); }

__device__ __forceinline__ void gld16(const _Float16* g, char* lds) {
  __builtin_amdgcn_global_load_lds(
      (const __attribute__((address_space(1))) unsigned int*)g,
      (__attribute__((address_space(3))) unsigned int*)lds, 16, 0, 0);
}

__device__ __forceinline__ void grid_bar(unsigned* cnt, unsigned target) {
  __syncthreads();                      // drains vmcnt (h stores) once per step
  if (threadIdx.x == 0) {
    __hip_atomic_fetch_add(cnt, 1u, __ATOMIC_RELEASE, __HIP_MEMORY_SCOPE_AGENT);
    while (__hip_atomic_load(cnt, __ATOMIC_RELAXED, __HIP_MEMORY_SCOPE_AGENT) < target)
      __builtin_amdgcn_s_sleep(2);
    __builtin_amdgcn_fence(__ATOMIC_ACQUIRE, "agent");
  }
  __syncthreads();
}

// ---- weight repack fp32 -> fp16 into per-block packed rows ----
__global__ void convert_weights(const float* __restrict__ Wih0, const float* __restrict__ Whh0,
                                const float* __restrict__ Wih1, const float* __restrict__ Whh1,
                                const float* __restrict__ Wlin,
                                _Float16* __restrict__ Wp0, _Float16* __restrict__ Wp1,
                                _Float16* __restrict__ Wlp) {
  const unsigned N0 = 96u*64u*K0P, N1 = 128u*48u*K1P, N2 = 16u*HDIM;
  const unsigned NT = N0 + N1 + N2;
  for (unsigned i = blockIdx.x*blockDim.x + threadIdx.x; i < NT; i += gridDim.x*blockDim.x) {
    if (i < N0) {           // L0: [blk 96][p 64][k 1600], p = gate*16 + j
      unsigned blk = i / (64u*K0P), r = i - blk*64u*K0P;
      unsigned p = r / K0P, kk = r - p*K0P;
      unsigned srow = (p>>4)*HDIM + blk*16 + (p&15);
      float v;
      if (kk < 64u) v = (kk < 6u) ? Wih0[srow*6 + kk] : 0.f;
      else          v = Whh0[(size_t)srow*HDIM + (kk-64u)];
      Wp0[i] = (_Float16)v;
    } else if (i < N0 + N1) { // L1: [blk 128][p 48][k 3072], p = gate*12 + j
      unsigned ii = i - N0;
      unsigned blk = ii / (48u*K1P), r = ii - blk*48u*K1P;
      unsigned p = r / K1P, kk = r - p*K1P;
      unsigned srow = (p/12u)*HDIM + blk*12 + (p%12u);
      float v = (kk < (unsigned)HDIM) ? Wih1[(size_t)srow*HDIM + kk]
                                      : Whh1[(size_t)srow*HDIM + (kk-HDIM)];
      Wp1[ii] = (_Float16)v;
    } else {                 // final linear 16 x 1536 (rows >=5 zero)
      unsigned ii = i - N0 - N1;
      unsigned rr = ii / HDIM, k = ii - rr*HDIM;
      Wlp[ii] = (_Float16)(rr < 5 ? Wlin[rr*HDIM + k] : 0.f);
    }
  }
}

__global__ __launch_bounds__(256, 1) void lstm_persistent(
    const float* __restrict__ xall,
    const float* __restrict__ bih0, const float* __restrict__ bhh0,
    const float* __restrict__ bih1, const float* __restrict__ bhh1,
    const float* __restrict__ blin,
    const _Float16* __restrict__ Wp0, const _Float16* __restrict__ Wp1,
    const _Float16* __restrict__ Wlp,
    _Float16* __restrict__ h0b, _Float16* __restrict__ h1b,
    unsigned* __restrict__ cnt, float* __restrict__ out)
{
  extern __shared__ __align__(16) char smem[];
  char*  park = smem + SM_PARK;
  float* cst  = (float*)(smem + SM_CST);
  float* bg   = (float*)(smem + SM_BG);
  float* gbuf = (float*)smem;            // epilogue overlay on staging

  const int tid = threadIdx.x, bid = blockIdx.x;
  const int wv = tid >> 6, lane = tid & 63, q = lane >> 4, l15 = lane & 15;
  const int BH = BATCH*HDIM;
  unsigned barc = 0;

  // DMA lane offsets: instr i stages rows [wv*32+i*4, +4), swizzled cols.
  int dmaoff[8];
#pragma unroll
  for (int i = 0; i < 8; ++i) {
    int m = wv*32 + i*4 + (lane>>4), w16 = lane & 15;
    int u = (w16 & 8) | ((w16 ^ (m & 7)) & 7);
    dmaoff[i] = m*HDIM + u*8;
  }
  // A-frag LDS byte addrs within a window buffer (this wave reads chunk #wv).
  const int uA = wv*4 + q;
  int addrA[8];
#pragma unroll
  for (int mt = 0; mt < 8; ++mt) {
    int m = mt*16 + l15;
    int swz = (uA & 8) | ((uA ^ (m & 7)) & 7);
    addrA[mt] = m*256 + swz*16;
  }

  if (bid < NB_L0) {
    // ================= LAYER 0: N=64 gate-cols (16 h-cols), K'=1600, 13 windows
    for (int p = tid; p < 64; p += 256) {
      int srow = (p>>4)*HDIM + (bid<<4) + (p&15);
      bg[p] = bih0[srow] + bhh0[srow];
    }
    for (int i = tid; i < BATCH*16; i += 256) cst[i] = 0.f;
    // B-frags resident: bw[wi][nt] = chunk (4*wi+wv), ntile nt
    f16x8 bw[13][4];
#pragma unroll
    for (int wi = 0; wi < 13; ++wi)
#pragma unroll
      for (int nt = 0; nt < 4; ++nt)
        bw[wi][nt] = *(const f16x8*)(Wp0 + ((size_t)(bid*64 + nt*16 + l15))*K0P
                                         + (4*wi + wv)*32 + q*8);
    __syncthreads();

#pragma unroll 1
    for (int s = 0; s < TSTEPS; ++s) {
      const _Float16* h0r = h0b + ((s+1)&1)*BH;
      _Float16*       h0w = h0b + (s&1)*BH;
      const float*    xs  = xall + (size_t)s*BATCH*6;

      // ---- prologue: DMA window1; plain-stage window0 (x-part + h cols 0..63)
#pragma unroll
      for (int i = 0; i < 8; ++i)
        gld16(h0r + 64 + dmaoff[i], smem + 32768 + (wv*8+i)*1024);
#pragma unroll
      for (int i = 0; i < 4; ++i) {          // x-part, slots u<8 of window0
        int sidx = i*256 + tid, m = sidx>>3, w8 = sidx&7;
        int u = w8 ^ (m & 7);
        f16x8 v = {0,0,0,0,0,0,0,0};
        if (u == 0) {
#pragma unroll
          for (int j = 0; j < 6; ++j) v[j] = (_Float16)xs[m*6 + j];
        }
        *(f16x8*)(smem + m*256 + w8*16) = v;
      }
#pragma unroll
      for (int i = 0; i < 4; ++i) {          // h cols [0,64) -> slots w in [8,16)
        int sidx = i*256 + tid, m = sidx>>3, w8 = sidx&7;
        int u8 = (w8 ^ (m & 7)) & 7;
        f16x8 hv = *(const f16x8*)(h0r + m*HDIM + u8*8);
        *(f16x8*)(smem + m*256 + (8 + w8)*16) = hv;
      }
      f32x4 acc[8][4];
#pragma unroll
      for (int mt = 0; mt < 8; ++mt)
#pragma unroll
        for (int nt = 0; nt < 4; ++nt) { f32x4 z = {0,0,0,0}; acc[mt][nt] = z; }

      // ---- K-loop: 13 windows
#pragma unroll
      for (int wi = 0; wi < 13; ++wi) {
        if (wi == 12)      WAITVM0();
        else if (wi >= 1)  WAITVM8();
        LDSBAR();
        if (wi + 2 < 13) {                   // DMA window wi+2 (cols 128w-64)
          const _Float16* src = h0r + (wi+2)*128 - 64;
          char* dst = smem + ((wi+2)%3)*32768;
#pragma unroll
          for (int i = 0; i < 8; ++i) gld16(src + dmaoff[i], dst + (wv*8+i)*1024);
        }
        if (4*wi + wv < 50) {                // wave's chunk exists
          const char* bs = smem + (wi%3)*32768;
#pragma unroll
          for (int mt = 0; mt < 8; ++mt) {
            f16x8 a = *(const f16x8*)(bs + addrA[mt]);
#pragma unroll
            for (int nt = 0; nt < 4; ++nt)
              acc[mt][nt] = MFMA(a, bw[wi][nt], acc[mt][nt]);
          }
        }
      }
      LDSBAR();

      // ---- staggered K-reduction into gbuf [64 cols][stride 132 f32]
#pragma unroll
      for (int r = 0; r < 4; ++r) {
        int nt = (wv + r) & 3;
#pragma unroll
        for (int mt = 0; mt < 8; ++mt) {
          f32x4 av = (nt==0)?acc[mt][0]:(nt==1)?acc[mt][1]:(nt==2)?acc[mt][2]:acc[mt][3];
          float* p = gbuf + (nt*16 + l15)*132 + (mt*16 + q*4);
          if (r == 0) *(f32x4*)p = av;
          else        { f32x4 o = *(const f32x4*)p; *(f32x4*)p = o + av; }
        }
        LDSBAR();
      }
      // ---- cell update + h0 write
#pragma unroll
      for (int e = 0; e < 8; ++e) {
        int idx = e*256 + tid, m = idx>>4, j = idx&15;
        float gi = gbuf[j*132 + m]        + bg[j];
        float gf = gbuf[(16+j)*132 + m]   + bg[16+j];
        float gg = gbuf[(32+j)*132 + m]   + bg[32+j];
        float go = gbuf[(48+j)*132 + m]   + bg[48+j];
        float co = cst[m*16 + j];
        float cn = sgf(gf)*co + sgf(gi)*thf(gg);
        cst[m*16 + j] = cn;
        h0w[(size_t)m*HDIM + (bid<<4) + j] = (_Float16)(sgf(go)*thf(cn));
      }
      barc += NBLK; grid_bar(cnt, barc);
    }
    barc += NBLK; grid_bar(cnt, barc);       // tail slot (pairs with L1 slot 0)
  } else {
    // ================= LAYER 1: N=48 gate-cols (12 h1-cols), K=3072, 24 windows
    const int bid1 = bid - NB_L0;
    for (int p = tid; p < 48; p += 256) {
      int srow = (p/12)*HDIM + bid1*12 + (p%12);
      bg[p] = bih1[srow] + bhh1[srow];
    }
    for (int i = tid; i < 64*12; i += 256) cst[i] = 0.f;
    f16x8 bw1[20][3];                        // windows 0..19 in regs
#pragma unroll
    for (int wi = 0; wi < 20; ++wi)
#pragma unroll
      for (int nt = 0; nt < 3; ++nt)
        bw1[wi][nt] = *(const f16x8*)(Wp1 + ((size_t)(bid1*48 + nt*16 + l15))*K1P
                                          + (4*wi + wv)*32 + q*8);
    // windows 20..23 parked in LDS: park[cl][nt][lane]
    for (int idx = tid; idx < 16*3*64; idx += 256) {
      int cl = idx/192, rem = idx - cl*192, nt = rem>>6, l = rem&63;
      f16x8 v = *(const f16x8*)(Wp1 + ((size_t)(bid1*48 + nt*16 + (l&15)))*K1P
                                    + (80 + cl)*32 + (l>>4)*8);
      *(f16x8*)(park + idx*16) = v;
    }
    __syncthreads();
    barc += NBLK; grid_bar(cnt, barc);       // slot 0 (idle)

#pragma unroll 1
    for (int s = 1; s <= TSTEPS; ++s) {
      const _Float16* h0r = h0b + ((s-1)&1)*BH;   // h0(s-1)
      const _Float16* h1r = h1b + (s&1)*BH;       // h1(s-2)
      _Float16*       h1w = h1b + ((s-1)&1)*BH;   // h1(s-1)

      // prologue: DMA windows 0,1 (h0 cols 0..255)
#pragma unroll
      for (int i = 0; i < 8; ++i) gld16(h0r +   0 + dmaoff[i], smem +     0 + (wv*8+i)*1024);
#pragma unroll
      for (int i = 0; i < 8; ++i) gld16(h0r + 128 + dmaoff[i], smem + 32768 + (wv*8+i)*1024);
      f32x4 acc[8][3];
#pragma unroll
      for (int mt = 0; mt < 8; ++mt)
#pragma unroll
        for (int nt = 0; nt < 3; ++nt) { f32x4 z = {0,0,0,0}; acc[mt][nt] = z; }

#pragma unroll
      for (int wi = 0; wi < 24; ++wi) {
        if (wi == 23) WAITVM0(); else WAITVM8();
        LDSBAR();
        if (wi + 2 < 24) {
          int wn = wi + 2;
          const _Float16* src = (wn < 12) ? (h0r + wn*128) : (h1r + (wn-12)*128);
          char* dst = smem + (wn%3)*32768;
#pragma unroll
          for (int i = 0; i < 8; ++i) gld16(src + dmaoff[i], dst + (wv*8+i)*1024);
        }
        const char* bs = smem + (wi%3)*32768;
        if (wi < 20) {
#pragma unroll
          for (int mt = 0; mt < 8; ++mt) {
            f16x8 a = *(const f16x8*)(bs + addrA[mt]);
#pragma unroll
            for (int nt = 0; nt < 3; ++nt)
              acc[mt][nt] = MFMA(a, bw1[wi][nt], acc[mt][nt]);
          }
        } else {
          f16x8 p0 = *(const f16x8*)(park + ((((wi-20)*4 + wv)*3 + 0)*64 + lane)*16);
          f16x8 p1 = *(const f16x8*)(park + ((((wi-20)*4 + wv)*3 + 1)*64 + lane)*16);
          f16x8 p2 = *(const f16x8*)(park + ((((wi-20)*4 + wv)*3 + 2)*64 + lane)*16);
#pragma unroll
          for (int mt = 0; mt < 8; ++mt) {
            f16x8 a = *(const f16x8*)(bs + addrA[mt]);
            acc[mt][0] = MFMA(a, p0, acc[mt][0]);
            acc[mt][1] = MFMA(a, p1, acc[mt][1]);
            acc[mt][2] = MFMA(a, p2, acc[mt][2]);
          }
        }
      }
      LDSBAR();

#pragma unroll
      for (int r = 0; r < 4; ++r) {
        int nt = (wv + r) & 3;
        if (nt < 3) {
#pragma unroll
          for (int mt = 0; mt < 8; ++mt) {
            f32x4 av = (nt==0)?acc[mt][0]:(nt==1)?acc[mt][1]:acc[mt][2];
            float* p = gbuf + (nt*16 + l15)*132 + (mt*16 + q*4);
            if (r == 0 || (r == 1 && wv == 3)) {
              // first writer per ntile: round 0 always writes; ntile handled
              // by no wave at r==0 only when (wv==3,r==0 -> nt=3 skipped), its
              // r==1 writer is wv==3? no: nt==wv&3 at r0 writes; wv=3 r0 skips,
              // so ntiles 0..2 are written at r0 by wv==nt. wv3 first touches
              // nt=0 at r1 -> must ADD (already written). Only r==0 writes.
            }
            if (r == 0) *(f32x4*)p = av;
            else        { f32x4 o = *(const f32x4*)p; *(f32x4*)p = o + av; }
          }
        }
        LDSBAR();
      }
#pragma unroll
      for (int e = 0; e < 8; ++e) {
        int idx = e*256 + tid, m = idx>>4, j = idx&15;
        if (j < 12) {
          float gi = gbuf[j*132 + m]        + bg[j];
          float gf = gbuf[(12+j)*132 + m]   + bg[12+j];
          float gg = gbuf[(24+j)*132 + m]   + bg[24+j];
          float go = gbuf[(36+j)*132 + m]   + bg[36+j];
          float co = cst[m*12 + j];
          float cn = sgf(gf)*co + sgf(gi)*thf(gg);
          cst[m*12 + j] = cn;
          h1w[(size_t)m*HDIM + bid1*12 + j] = (_Float16)(sgf(go)*thf(cn));
        }
      }
      barc += NBLK; grid_bar(cnt, barc);
    }
  }

  // ---- final linear: out = h1(T-1) @ Wlin^T + blin (block 0 only) ----
  if (bid == 0) {
    const _Float16* h1r = h1b + ((TSTEPS-1)&1)*BH;
    f32x4 a8[8];
#pragma unroll
    for (int i = 0; i < 8; ++i) { f32x4 z = {0,0,0,0}; a8[i] = z; }
    for (int c = wv*12; c < wv*12 + 12; ++c) {
      f16x8 bf = *(const f16x8*)(Wlp + (size_t)l15*HDIM + c*32 + q*8);
#pragma unroll
      for (int mt = 0; mt < 8; ++mt) {
        f16x8 a = *(const f16x8*)(h1r + (size_t)(mt*16 + l15)*HDIM + c*32 + q*8);
        a8[mt] = MFMA(a, bf, a8[mt]);
      }
    }
    float* pl = (float*)smem;
#pragma unroll
    for (int mt = 0; mt < 8; ++mt)
#pragma unroll
      for (int rg = 0; rg < 4; ++rg)
        pl[wv*2048 + (mt*16 + q*4 + rg)*16 + l15] = a8[mt][rg];
    __syncthreads();
    for (int e = tid; e < 640; e += 256) {
      int b = e/5, o = e - 5*b;
      out[e] = blin[o] + pl[b*16+o] + pl[2048 + b*16+o] + pl[4096 + b*16+o] + pl[6144 + b*16+o];
    }
  }
}

extern "C" void kernel_launch(void* const* d_in, const int* in_sizes, int n_in,
                              void* d_out, int out_size, void* d_ws, size_t ws_size,
                              hipStream_t stream) {
  (void)in_sizes; (void)n_in; (void)out_size;
  if (ws_size < WS_NEED) return;

  const float* x    = (const float*)d_in[0];
  const float* Wih0 = (const float*)d_in[1];
  const float* Whh0 = (const float*)d_in[2];
  const float* bih0 = (const float*)d_in[3];
  const float* bhh0 = (const float*)d_in[4];
  const float* Wih1 = (const float*)d_in[5];
  const float* Whh1 = (const float*)d_in[6];
  const float* bih1 = (const float*)d_in[7];
  const float* bhh1 = (const float*)d_in[8];
  const float* Wlin = (const float*)d_in[9];
  const float* blin = (const float*)d_in[10];

  char* ws = (char*)d_ws;
  unsigned*  cnt = (unsigned*)ws;
  _Float16*  h0b = (_Float16*)(ws + OFF_H0);
  _Float16*  h1b = (_Float16*)(ws + OFF_H1);
  _Float16*  Wp0 = (_Float16*)(ws + OFF_WP0);
  _Float16*  Wp1 = (_Float16*)(ws + OFF_WP1);
  _Float16*  Wlp = (_Float16*)(ws + OFF_WLP);
  float*     out = (float*)d_out;

  hipMemsetAsync(ws, 0, OFF_WP0, stream);   // cnt + both h ping-pong buffers
  hipLaunchKernelGGL(convert_weights, dim3(4096), dim3(256), 0, stream,
                     Wih0, Whh0, Wih1, Whh1, Wlin, Wp0, Wp1, Wlp);

  hipFuncSetAttribute((const void*)lstm_persistent,
                      hipFuncAttributeMaxDynamicSharedMemorySize, 160*1024);

  void* args[13];
  args[0]  = (void*)&x;    args[1]  = (void*)&bih0; args[2]  = (void*)&bhh0;
  args[3]  = (void*)&bih1; args[4]  = (void*)&bhh1; args[5]  = (void*)&blin;
  args[6]  = (void*)&Wp0;  args[7]  = (void*)&Wp1;  args[8]  = (void*)&Wlp;
  args[9]  = (void*)&h0b;  args[10] = (void*)&h1b;  args[11] = (void*)&cnt;
  args[12] = (void*)&out;
  hipError_t err = hipLaunchCooperativeKernel((const void*)lstm_persistent,
                                              dim3(NBLK), dim3(256),
                                              args, (unsigned)SM_BYTES, stream);
  if (err != hipSuccess) {
    // fallback: plain launch (224 blocks <= 256 CUs co-reside at 1 block/CU)
    hipLaunchKernelGGL(lstm_persistent, dim3(NBLK), dim3(256), SM_BYTES, stream,
                       x, bih0, bhh0, bih1, bhh1, blin, Wp0, Wp1, Wlp,
                       h0b, h1b, cnt, out);
  }
}

// Round 4
// 28007.458 us; speedup vs baseline: 1.8413x; 1.0595x over previous
//
// Round 4: weights stay VGPR-resident (round-3 structure). Barrier rework:
// - L0 group (96 blks) and L1 group (128 blks) have SEPARATE 8-line split
//   counters (12/16 adds per line in parallel vs 224 serial on one line).
// - h0 ring depth 4: L0 runs ahead of L1 (gated at lead<=3 by c1 lag check);
//   L1 polls c0 (normally already satisfied). Chains decouple.
#include <hip/hip_runtime.h>

#define TSTEPS 1024
#define BATCH  128
#define HDIM   1536
#define NB_L0  96
#define NB_L1  128
#define NBLK   (NB_L0 + NB_L1)
#define K0P    1600    // L0 packed K: [0,64)=x+pad, [64,1600)=W_hh0
#define K1P    3072    // L1 packed K: [0,1536)=W_ih1, [1536,3072)=W_hh1

typedef _Float16 f16x8 __attribute__((ext_vector_type(8)));
typedef float    f32x4 __attribute__((ext_vector_type(4)));

// ---- workspace layout (bytes) ----
#define OFF_C0   0ul                                    // 8 lines x 128B
#define OFF_C1   1024ul                                 // 8 lines x 128B
#define OFF_H0   4096ul                                 // ring of 4 slots
#define OFF_H1   (OFF_H0 + 4ul*BATCH*HDIM*2)            // 2 slots
#define OFF_WP0  (OFF_H1 + 2ul*BATCH*HDIM*2)
#define OFF_WP1  (OFF_WP0 + 96ul*64*K0P*2)
#define OFF_WLP  (OFF_WP1 + 128ul*48*K1P*2)
#define WS_NEED  (OFF_WLP + 16ul*HDIM*2)                // ~59.8 MB

// ---- dynamic LDS layout (bytes) ----
#define SM_PARK  98304     // 3 x 32KB staging windows first
#define SM_CST   147456    // park: 16 chunks x 3KB = 48KB (L1 only)
#define SM_BG    155648
#define SM_BYTES 155904

#define MFMA(a,b,c) __builtin_amdgcn_mfma_f32_16x16x32_f16(a,b,c,0,0,0)
#define LDSBAR()  asm volatile("s_waitcnt lgkmcnt(0)\n\ts_barrier" ::: "memory")
#define WAITVM8() asm volatile("s_waitcnt vmcnt(8)" ::: "memory")
#define WAITVM0() asm volatile("s_waitcnt vmcnt(0)" ::: "memory")

__device__ __forceinline__ float sgf(float x) { return 1.f/(1.f + __expf(-x)); }
__device__ __forceinline__ float thf(float x) { float e = __expf(2.f*x); return 1.f - 2.f/(e+1.f); }

__device__ __forceinline__ void gld16(const _Float16* g, char* lds) {
  __builtin_amdgcn_global_load_lds(
      (const __attribute__((address_space(1))) unsigned int*)g,
      (__attribute__((address_space(3))) unsigned int*)lds, 16, 0, 0);
}

// Group barrier: add 1 to my line (release), spin until all 8 lines hit
// per-line target, acquire, resync. 12 (L0) / 16 (L1) adds per line run in
// parallel across lines instead of 224 serialized RMWs on one line.
__device__ __forceinline__ void group_bar(unsigned* lines, unsigned target, int tid) {
  __syncthreads();   // all stores (incl. h) issued; drains vmcnt/lgkm
  if (tid == 0)
    __hip_atomic_fetch_add(lines + (blockIdx.x & 7)*32, 1u,
                           __ATOMIC_RELEASE, __HIP_MEMORY_SCOPE_AGENT);
  if (tid < 8) {
    while (__hip_atomic_load(lines + tid*32, __ATOMIC_RELAXED,
                             __HIP_MEMORY_SCOPE_AGENT) < target)
      __builtin_amdgcn_s_sleep(1);
    __builtin_amdgcn_fence(__ATOMIC_ACQUIRE, "agent");
  }
  __syncthreads();
}

// Cross-group wait (no add): poll other group's 8 lines to target, acquire.
__device__ __forceinline__ void wait_group(unsigned* lines, unsigned target, int tid) {
  if (tid < 8) {
    while (__hip_atomic_load(lines + tid*32, __ATOMIC_RELAXED,
                             __HIP_MEMORY_SCOPE_AGENT) < target)
      __builtin_amdgcn_s_sleep(1);
    __builtin_amdgcn_fence(__ATOMIC_ACQUIRE, "agent");
  }
  __syncthreads();
}

// ---- weight repack fp32 -> fp16 into per-block packed rows ----
__global__ void convert_weights(const float* __restrict__ Wih0, const float* __restrict__ Whh0,
                                const float* __restrict__ Wih1, const float* __restrict__ Whh1,
                                const float* __restrict__ Wlin,
                                _Float16* __restrict__ Wp0, _Float16* __restrict__ Wp1,
                                _Float16* __restrict__ Wlp) {
  const unsigned N0 = 96u*64u*K0P, N1 = 128u*48u*K1P, N2 = 16u*HDIM;
  const unsigned NT = N0 + N1 + N2;
  for (unsigned i = blockIdx.x*blockDim.x + threadIdx.x; i < NT; i += gridDim.x*blockDim.x) {
    if (i < N0) {           // L0: [blk 96][p 64][k 1600], p = gate*16 + j
      unsigned blk = i / (64u*K0P), r = i - blk*64u*K0P;
      unsigned p = r / K0P, kk = r - p*K0P;
      unsigned srow = (p>>4)*HDIM + blk*16 + (p&15);
      float v;
      if (kk < 64u) v = (kk < 6u) ? Wih0[srow*6 + kk] : 0.f;
      else          v = Whh0[(size_t)srow*HDIM + (kk-64u)];
      Wp0[i] = (_Float16)v;
    } else if (i < N0 + N1) { // L1: [blk 128][p 48][k 3072], p = gate*12 + j
      unsigned ii = i - N0;
      unsigned blk = ii / (48u*K1P), r = ii - blk*48u*K1P;
      unsigned p = r / K1P, kk = r - p*K1P;
      unsigned srow = (p/12u)*HDIM + blk*12 + (p%12u);
      float v = (kk < (unsigned)HDIM) ? Wih1[(size_t)srow*HDIM + kk]
                                      : Whh1[(size_t)srow*HDIM + (kk-HDIM)];
      Wp1[ii] = (_Float16)v;
    } else {                 // final linear 16 x 1536 (rows >=5 zero)
      unsigned ii = i - N0 - N1;
      unsigned rr = ii / HDIM, k = ii - rr*HDIM;
      Wlp[ii] = (_Float16)(rr < 5 ? Wlin[rr*HDIM + k] : 0.f);
    }
  }
}

__global__ __launch_bounds__(256, 1) void lstm_persistent(
    const float* __restrict__ xall,
    const float* __restrict__ bih0, const float* __restrict__ bhh0,
    const float* __restrict__ bih1, const float* __restrict__ bhh1,
    const float* __restrict__ blin,
    const _Float16* __restrict__ Wp0, const _Float16* __restrict__ Wp1,
    const _Float16* __restrict__ Wlp,
    _Float16* __restrict__ h0b, _Float16* __restrict__ h1b,
    unsigned* __restrict__ c0l, unsigned* __restrict__ c1l,
    float* __restrict__ out)
{
  extern __shared__ __align__(16) char smem[];
  char*  park = smem + SM_PARK;
  float* cst  = (float*)(smem + SM_CST);
  float* bg   = (float*)(smem + SM_BG);
  float* gbuf = (float*)smem;            // epilogue overlay on staging

  const int tid = threadIdx.x, bid = blockIdx.x;
  const int wv = tid >> 6, lane = tid & 63, q = lane >> 4, l15 = lane & 15;
  const int BH = BATCH*HDIM;

  // DMA lane offsets: instr i stages rows [wv*32+i*4, +4), swizzled cols.
  int dmaoff[8];
#pragma unroll
  for (int i = 0; i < 8; ++i) {
    int m = wv*32 + i*4 + (lane>>4), w16 = lane & 15;
    int u = (w16 & 8) | ((w16 ^ (m & 7)) & 7);
    dmaoff[i] = m*HDIM + u*8;
  }
  // A-frag LDS byte addrs within a window buffer (this wave reads chunk #wv).
  const int uA = wv*4 + q;
  int addrA[8];
#pragma unroll
  for (int mt = 0; mt < 8; ++mt) {
    int m = mt*16 + l15;
    int swz = (uA & 8) | ((uA ^ (m & 7)) & 7);
    addrA[mt] = m*256 + swz*16;
  }

  if (bid < NB_L0) {
    // ================= LAYER 0: N=64 gate-cols (16 h-cols), K'=1600, 13 windows
    for (int p = tid; p < 64; p += 256) {
      int srow = (p>>4)*HDIM + (bid<<4) + (p&15);
      bg[p] = bih0[srow] + bhh0[srow];
    }
    for (int i = tid; i < BATCH*16; i += 256) cst[i] = 0.f;
    f16x8 bw[13][4];
#pragma unroll
    for (int wi = 0; wi < 13; ++wi)
#pragma unroll
      for (int nt = 0; nt < 4; ++nt)
        bw[wi][nt] = *(const f16x8*)(Wp0 + ((size_t)(bid*64 + nt*16 + l15))*K0P
                                         + (4*wi + wv)*32 + q*8);
    __syncthreads();

#pragma unroll 1
    for (int s = 0; s < TSTEPS; ++s) {
      // ring-overwrite guard: slot s&3 was read by L1 step s-3; wait it done.
      if (s >= 4) wait_group(c1l, 16u*(unsigned)(s-3), tid);

      const _Float16* h0r = h0b + (size_t)((s+3)&3)*BH;   // h0(s-1)
      _Float16*       h0w = h0b + (size_t)(s&3)*BH;       // h0(s)
      const float*    xs  = xall + (size_t)s*BATCH*6;

      // ---- prologue: DMA window1; plain-stage window0 (x-part + h cols 0..63)
#pragma unroll
      for (int i = 0; i < 8; ++i)
        gld16(h0r + 64 + dmaoff[i], smem + 32768 + (wv*8+i)*1024);
#pragma unroll
      for (int i = 0; i < 4; ++i) {          // x-part, slots u<8 of window0
        int sidx = i*256 + tid, m = sidx>>3, w8 = sidx&7;
        int u = w8 ^ (m & 7);
        f16x8 v = {0,0,0,0,0,0,0,0};
        if (u == 0) {
#pragma unroll
          for (int j = 0; j < 6; ++j) v[j] = (_Float16)xs[m*6 + j];
        }
        *(f16x8*)(smem + m*256 + w8*16) = v;
      }
#pragma unroll
      for (int i = 0; i < 4; ++i) {          // h cols [0,64) -> slots w in [8,16)
        int sidx = i*256 + tid, m = sidx>>3, w8 = sidx&7;
        int u8 = (w8 ^ (m & 7)) & 7;
        f16x8 hv = *(const f16x8*)(h0r + m*HDIM + u8*8);
        *(f16x8*)(smem + m*256 + (8 + w8)*16) = hv;
      }
      f32x4 acc[8][4];
#pragma unroll
      for (int mt = 0; mt < 8; ++mt)
#pragma unroll
        for (int nt = 0; nt < 4; ++nt) { f32x4 z = {0,0,0,0}; acc[mt][nt] = z; }

      // ---- K-loop: 13 windows
#pragma unroll
      for (int wi = 0; wi < 13; ++wi) {
        if (wi == 12)      WAITVM0();
        else if (wi >= 1)  WAITVM8();
        LDSBAR();
        if (wi + 2 < 13) {                   // DMA window wi+2 (cols 128w-64)
          const _Float16* src = h0r + (wi+2)*128 - 64;
          char* dst = smem + ((wi+2)%3)*32768;
#pragma unroll
          for (int i = 0; i < 8; ++i) gld16(src + dmaoff[i], dst + (wv*8+i)*1024);
        }
        if (4*wi + wv < 50) {                // wave's chunk exists
          const char* bs = smem + (wi%3)*32768;
#pragma unroll
          for (int mt = 0; mt < 8; ++mt) {
            f16x8 a = *(const f16x8*)(bs + addrA[mt]);
#pragma unroll
            for (int nt = 0; nt < 4; ++nt)
              acc[mt][nt] = MFMA(a, bw[wi][nt], acc[mt][nt]);
          }
        }
      }
      LDSBAR();

      // ---- staggered K-reduction into gbuf [64 cols][stride 132 f32]
#pragma unroll
      for (int r = 0; r < 4; ++r) {
        int nt = (wv + r) & 3;
#pragma unroll
        for (int mt = 0; mt < 8; ++mt) {
          f32x4 av = (nt==0)?acc[mt][0]:(nt==1)?acc[mt][1]:(nt==2)?acc[mt][2]:acc[mt][3];
          float* p = gbuf + (nt*16 + l15)*132 + (mt*16 + q*4);
          if (r == 0) *(f32x4*)p = av;
          else        { f32x4 o = *(const f32x4*)p; *(f32x4*)p = o + av; }
        }
        LDSBAR();
      }
      // ---- cell update + h0 write
#pragma unroll
      for (int e = 0; e < 8; ++e) {
        int idx = e*256 + tid, m = idx>>4, j = idx&15;
        float gi = gbuf[j*132 + m]        + bg[j];
        float gf = gbuf[(16+j)*132 + m]   + bg[16+j];
        float gg = gbuf[(32+j)*132 + m]   + bg[32+j];
        float go = gbuf[(48+j)*132 + m]   + bg[48+j];
        float co = cst[m*16 + j];
        float cn = sgf(gf)*co + sgf(gi)*thf(gg);
        cst[m*16 + j] = cn;
        h0w[(size_t)m*HDIM + (bid<<4) + j] = (_Float16)(sgf(go)*thf(cn));
      }
      group_bar(c0l, 12u*(unsigned)(s+1), tid);   // L0-only barrier
    }
  } else {
    // ================= LAYER 1: N=48 gate-cols (12 h1-cols), K=3072, 24 windows
    const int bid1 = bid - NB_L0;
    for (int p = tid; p < 48; p += 256) {
      int srow = (p/12)*HDIM + bid1*12 + (p%12);
      bg[p] = bih1[srow] + bhh1[srow];
    }
    for (int i = tid; i < 64*12; i += 256) cst[i] = 0.f;
    f16x8 bw1[20][3];                        // windows 0..19 in regs
#pragma unroll
    for (int wi = 0; wi < 20; ++wi)
#pragma unroll
      for (int nt = 0; nt < 3; ++nt)
        bw1[wi][nt] = *(const f16x8*)(Wp1 + ((size_t)(bid1*48 + nt*16 + l15))*K1P
                                          + (4*wi + wv)*32 + q*8);
    // windows 20..23 parked in LDS: park[cl][nt][lane]
    for (int idx = tid; idx < 16*3*64; idx += 256) {
      int cl = idx/192, rem = idx - cl*192, nt = rem>>6, l = rem&63;
      f16x8 v = *(const f16x8*)(Wp1 + ((size_t)(bid1*48 + nt*16 + (l&15)))*K1P
                                    + (80 + cl)*32 + (l>>4)*8);
      *(f16x8*)(park + idx*16) = v;
    }
    __syncthreads();

#pragma unroll 1
    for (int s = 1; s <= TSTEPS; ++s) {
      // need h0(s-1): L0 finished step s-1 <=> c0 lines >= 12*s
      wait_group(c0l, 12u*(unsigned)s, tid);

      const _Float16* h0r = h0b + (size_t)((s-1)&3)*BH;   // h0(s-1)
      const _Float16* h1r = h1b + (size_t)(s&1)*BH;       // h1(s-2)
      _Float16*       h1w = h1b + (size_t)((s-1)&1)*BH;   // h1(s-1)

      // prologue: DMA windows 0,1 (h0 cols 0..255)
#pragma unroll
      for (int i = 0; i < 8; ++i) gld16(h0r +   0 + dmaoff[i], smem +     0 + (wv*8+i)*1024);
#pragma unroll
      for (int i = 0; i < 8; ++i) gld16(h0r + 128 + dmaoff[i], smem + 32768 + (wv*8+i)*1024);
      f32x4 acc[8][3];
#pragma unroll
      for (int mt = 0; mt < 8; ++mt)
#pragma unroll
        for (int nt = 0; nt < 3; ++nt) { f32x4 z = {0,0,0,0}; acc[mt][nt] = z; }

#pragma unroll
      for (int wi = 0; wi < 24; ++wi) {
        if (wi == 23) WAITVM0(); else WAITVM8();
        LDSBAR();
        if (wi + 2 < 24) {
          int wn = wi + 2;
          const _Float16* src = (wn < 12) ? (h0r + wn*128) : (h1r + (wn-12)*128);
          char* dst = smem + (wn%3)*32768;
#pragma unroll
          for (int i = 0; i < 8; ++i) gld16(src + dmaoff[i], dst + (wv*8+i)*1024);
        }
        const char* bs = smem + (wi%3)*32768;
        if (wi < 20) {
#pragma unroll
          for (int mt = 0; mt < 8; ++mt) {
            f16x8 a = *(const f16x8*)(bs + addrA[mt]);
#pragma unroll
            for (int nt = 0; nt < 3; ++nt)
              acc[mt][nt] = MFMA(a, bw1[wi][nt], acc[mt][nt]);
          }
        } else {
          f16x8 p0 = *(const f16x8*)(park + ((((wi-20)*4 + wv)*3 + 0)*64 + lane)*16);
          f16x8 p1 = *(const f16x8*)(park + ((((wi-20)*4 + wv)*3 + 1)*64 + lane)*16);
          f16x8 p2 = *(const f16x8*)(park + ((((wi-20)*4 + wv)*3 + 2)*64 + lane)*16);
#pragma unroll
          for (int mt = 0; mt < 8; ++mt) {
            f16x8 a = *(const f16x8*)(bs + addrA[mt]);
            acc[mt][0] = MFMA(a, p0, acc[mt][0]);
            acc[mt][1] = MFMA(a, p1, acc[mt][1]);
            acc[mt][2] = MFMA(a, p2, acc[mt][2]);
          }
        }
      }
      LDSBAR();

      // ---- staggered K-reduction (3 ntiles)
#pragma unroll
      for (int r = 0; r < 4; ++r) {
        int nt = (wv + r) & 3;
        if (nt < 3) {
#pragma unroll
          for (int mt = 0; mt < 8; ++mt) {
            f32x4 av = (nt==0)?acc[mt][0]:(nt==1)?acc[mt][1]:acc[mt][2];
            float* p = gbuf + (nt*16 + l15)*132 + (mt*16 + q*4);
            if (r == 0) *(f32x4*)p = av;
            else        { f32x4 o = *(const f32x4*)p; *(f32x4*)p = o + av; }
          }
        }
        LDSBAR();
      }
#pragma unroll
      for (int e = 0; e < 8; ++e) {
        int idx = e*256 + tid, m = idx>>4, j = idx&15;
        if (j < 12) {
          float gi = gbuf[j*132 + m]        + bg[j];
          float gf = gbuf[(12+j)*132 + m]   + bg[12+j];
          float gg = gbuf[(24+j)*132 + m]   + bg[24+j];
          float go = gbuf[(36+j)*132 + m]   + bg[36+j];
          float co = cst[m*12 + j];
          float cn = sgf(gf)*co + sgf(gi)*thf(gg);
          cst[m*12 + j] = cn;
          h1w[(size_t)m*HDIM + bid1*12 + j] = (_Float16)(sgf(go)*thf(cn));
        }
      }
      group_bar(c1l, 16u*(unsigned)s, tid);   // L1-only barrier
    }

    // ---- final linear: out = h1(T-1) @ Wlin^T + blin (first L1 block) ----
    if (bid == NB_L0) {
      const _Float16* h1r = h1b + (size_t)((TSTEPS-1)&1)*BH;
      f32x4 a8[8];
#pragma unroll
      for (int i = 0; i < 8; ++i) { f32x4 z = {0,0,0,0}; a8[i] = z; }
      for (int c = wv*12; c < wv*12 + 12; ++c) {
        f16x8 bf = *(const f16x8*)(Wlp + (size_t)l15*HDIM + c*32 + q*8);
#pragma unroll
        for (int mt = 0; mt < 8; ++mt) {
          f16x8 a = *(const f16x8*)(h1r + (size_t)(mt*16 + l15)*HDIM + c*32 + q*8);
          a8[mt] = MFMA(a, bf, a8[mt]);
        }
      }
      float* pl = (float*)smem;
#pragma unroll
      for (int mt = 0; mt < 8; ++mt)
#pragma unroll
        for (int rg = 0; rg < 4; ++rg)
          pl[wv*2048 + (mt*16 + q*4 + rg)*16 + l15] = a8[mt][rg];
      __syncthreads();
      for (int e = tid; e < 640; e += 256) {
        int b = e/5, o = e - 5*b;
        out[e] = blin[o] + pl[b*16+o] + pl[2048 + b*16+o] + pl[4096 + b*16+o] + pl[6144 + b*16+o];
      }
    }
  }
}

extern "C" void kernel_launch(void* const* d_in, const int* in_sizes, int n_in,
                              void* d_out, int out_size, void* d_ws, size_t ws_size,
                              hipStream_t stream) {
  (void)in_sizes; (void)n_in; (void)out_size;
  if (ws_size < WS_NEED) return;

  const float* x    = (const float*)d_in[0];
  const float* Wih0 = (const float*)d_in[1];
  const float* Whh0 = (const float*)d_in[2];
  const float* bih0 = (const float*)d_in[3];
  const float* bhh0 = (const float*)d_in[4];
  const float* Wih1 = (const float*)d_in[5];
  const float* Whh1 = (const float*)d_in[6];
  const float* bih1 = (const float*)d_in[7];
  const float* bhh1 = (const float*)d_in[8];
  const float* Wlin = (const float*)d_in[9];
  const float* blin = (const float*)d_in[10];

  char* ws = (char*)d_ws;
  unsigned*  c0l = (unsigned*)(ws + OFF_C0);
  unsigned*  c1l = (unsigned*)(ws + OFF_C1);
  _Float16*  h0b = (_Float16*)(ws + OFF_H0);
  _Float16*  h1b = (_Float16*)(ws + OFF_H1);
  _Float16*  Wp0 = (_Float16*)(ws + OFF_WP0);
  _Float16*  Wp1 = (_Float16*)(ws + OFF_WP1);
  _Float16*  Wlp = (_Float16*)(ws + OFF_WLP);
  float*     out = (float*)d_out;

  hipMemsetAsync(ws, 0, OFF_WP0, stream);   // counters + h rings
  hipLaunchKernelGGL(convert_weights, dim3(4096), dim3(256), 0, stream,
                     Wih0, Whh0, Wih1, Whh1, Wlin, Wp0, Wp1, Wlp);

  hipFuncSetAttribute((const void*)lstm_persistent,
                      hipFuncAttributeMaxDynamicSharedMemorySize, 160*1024);

  void* args[14];
  args[0]  = (void*)&x;    args[1]  = (void*)&bih0; args[2]  = (void*)&bhh0;
  args[3]  = (void*)&bih1; args[4]  = (void*)&bhh1; args[5]  = (void*)&blin;
  args[6]  = (void*)&Wp0;  args[7]  = (void*)&Wp1;  args[8]  = (void*)&Wlp;
  args[9]  = (void*)&h0b;  args[10] = (void*)&h1b;  args[11] = (void*)&c0l;
  args[12] = (void*)&c1l;  args[13] = (void*)&out;
  hipError_t err = hipLaunchCooperativeKernel((const void*)lstm_persistent,
                                              dim3(NBLK), dim3(256),
                                              args, (unsigned)SM_BYTES, stream);
  if (err != hipSuccess) {
    hipLaunchKernelGGL(lstm_persistent, dim3(NBLK), dim3(256), SM_BYTES, stream,
                       x, bih0, bhh0, bih1, bhh1, blin, Wp0, Wp1, Wlp,
                       h0b, h1b, c0l, c1l, out);
  }
}